// Round 2
// baseline (385.934 us; speedup 1.0000x reference)
//
#include <hip/hip_runtime.h>
#include <hip/hip_bf16.h>

#define NN 50000
#define EE 1600000
#define NT_N 391        // ceil(NN/128) node tiles
#define NIV 129         // piecewise-linear intervals (<=128 breakpoints + 1)

typedef float f32x4 __attribute__((ext_vector_type(4)));
typedef __bf16 bf16x8 __attribute__((ext_vector_type(8)));

// Piecewise-linear tables for the edge MLP (input is a SCALAR length):
//   out[c] = len * gA[iv][c] + gB[iv][c],  iv = #{ sorted breakpoints < len }
__device__ float gT[128];                       // sorted breakpoints
__device__ __align__(16) float gA[NIV * 128];
__device__ __align__(16) float gB[NIV * 128];

__device__ __forceinline__ float edge_len(int e, const int* __restrict__ eidx,
                                          const float* __restrict__ pos,
                                          const float* __restrict__ lp,
                                          const int* __restrict__ msk) {
    int ri = eidx[e];
    int ci = eidx[EE + e];
    const float* pr = msk[ri] ? lp : pos;
    const float* pc = msk[ci] ? lp : pos;
    float dx = pr[3 * ri + 0] - pc[3 * ci + 0];
    float dy = pr[3 * ri + 1] - pc[3 * ci + 1];
    float dz = pr[3 * ri + 2] - pc[3 * ci + 2];
    return sqrtf(dx * dx + dy * dy + dz * dz);
}

// ---- prep: breakpoints, ranks, and per-interval linear coefficients ------
// Single kernel (129 blocks x 128 threads). Every block recomputes the rank
// permutation locally (128x128 trivial ops) so there is no grid-wide dep.
// t_k = -b1[k]/W1[k]; W1[k]==0 never toggles -> t=+inf (sorts last).
// Interval i = (t_sorted[i-1], t_sorted[i]). Unit k active there iff
//   W1[k]>0: rank_k < i;  W1[k]<0: rank_k >= i;  W1[k]==0: b1[k]>0.
// Continuity of the PWL function makes boundary/tie choices immaterial.
__global__ void prep_tables(const float* __restrict__ Wd1, const float* __restrict__ bd1,
                            const float* __restrict__ Wd2, const float* __restrict__ bd2) {
    __shared__ float t_s[128];
    __shared__ int rank_s[128];
    const int c = threadIdx.x;           // output channel AND unit id
    float w1 = Wd1[c], b1 = bd1[c];
    float t = (w1 == 0.f) ? __builtin_inff() : (-b1 / w1);
    t_s[c] = t;
    __syncthreads();
    int rank = 0;
    for (int j = 0; j < 128; j++) {
        float tj = t_s[j];
        rank += (tj < t) || (tj == t && j < c);   // strict total order -> permutation
    }
    rank_s[c] = rank;
    if (blockIdx.x == 0) gT[rank] = t;            // publish sorted breakpoints
    __syncthreads();

    const int i = blockIdx.x;            // interval
    float a = 0.f, b = 0.f;
    for (int k = 0; k < 128; k++) {
        float w1k = Wd1[k], b1k = bd1[k];
        bool act = (w1k > 0.f) ? (rank_s[k] < i)
                 : (w1k < 0.f) ? (rank_s[k] >= i)
                               : (b1k > 0.f);
        if (act) {
            float w2 = Wd2[k * 128 + c];
            a = fmaf(w1k, w2, a);
            b = fmaf(b1k, w2, b);
        }
    }
    gA[i * 128 + c] = a;
    gB[i * 128 + c] = b + bd2[c];
}

// ---- gather kernel: length AND interval index, once per edge -------------
// Hoists the 8-step binary search out of the stream kernel: the search's
// ~1k-cycle dependent LDS chain is paid once per edge here (amortized over
// 128 channels) instead of once per 32-lane row visit in the stream.
__global__ __launch_bounds__(256) void leniv_kernel(
    const int* __restrict__ eidx, const float* __restrict__ pos,
    const float* __restrict__ lp, const int* __restrict__ msk,
    float2* __restrict__ lenivp)
{
    __shared__ float ts[128];
    if (threadIdx.x < 128) ts[threadIdx.x] = gT[threadIdx.x];
    __syncthreads();
    int e = blockIdx.x * 256 + threadIdx.x;
    if (e < EE) {
        float lv = edge_len(e, eidx, pos, lp, msk);
        int lo = 0;            // iv = #{ ts[j] < lv }, result in [0,128]
#pragma unroll
        for (int s = 128; s > 0; s >>= 1) {
            int m = lo + s;
            if (m <= 128 && ts[m - 1] < lv) lo = m;
        }
        lenivp[e] = make_float2(lv, (float)lo);   // iv<=128 exact in f32
    }
}

// Fallback tier: length only (search stays in the stream kernel).
__global__ __launch_bounds__(256) void len_kernel(
    const int* __restrict__ eidx, const float* __restrict__ pos,
    const float* __restrict__ lp, const int* __restrict__ msk,
    float* __restrict__ len)
{
    int e = blockIdx.x * 256 + threadIdx.x;
    if (e < EE) len[e] = edge_len(e, eidx, pos, lp, msk);
}

// ---- edge kernel: pure stream ---------------------------------------------
// MODE 0: {len,iv} precomputed -> chain is one 16B broadcast load + L1-hot
//         table loads + FMA. MODE 1: len precomputed, search here.
// MODE 2: fully inline (correctness fallback, redundant per-lane gathers).
// 32 lanes per row-pair (f32x4 channels); 8 groups x 2 rows per 256-thread
// block per iteration -> 2x16B stream load + 2x16B store per chain.
template <int MODE>
__global__ __launch_bounds__(256) void edge_kernel(
    const float* __restrict__ ea, const float2* __restrict__ lenivp,
    const float* __restrict__ len,
    const int* __restrict__ eidx, const float* __restrict__ pos,
    const float* __restrict__ lp, const int* __restrict__ msk,
    float* __restrict__ oute)
{
    __shared__ float ts[128];
    if (MODE != 0) {
        if (threadIdx.x < 128) ts[threadIdx.x] = gT[threadIdx.x];
        __syncthreads();
    }

    const int g  = threadIdx.x >> 5;          // row-pair group within block
    const int c4 = (threadIdx.x & 31) * 4;    // channel base

    for (int r0 = (blockIdx.x * 8 + g) * 2; r0 < EE; r0 += gridDim.x * 16) {
        float len0, len1;
        int iv0, iv1;
        if (MODE == 0) {
            f32x4 lv = *(const f32x4*)&lenivp[r0];     // r0 even -> 16B aligned
            len0 = lv.x; iv0 = (int)lv.y;
            len1 = lv.z; iv1 = (int)lv.w;
        } else {
            len0 = (MODE == 1) ? len[r0]     : edge_len(r0, eidx, pos, lp, msk);
            len1 = (MODE == 1) ? len[r0 + 1] : edge_len(r0 + 1, eidx, pos, lp, msk);
            iv0 = 0; iv1 = 0;
#pragma unroll
            for (int s = 128; s > 0; s >>= 1) {
                int m0 = iv0 + s;
                if (m0 <= 128 && ts[m0 - 1] < len0) iv0 = m0;
                int m1 = iv1 + s;
                if (m1 <= 128 && ts[m1 - 1] < len1) iv1 = m1;
            }
        }

        const f32x4 a0 = *(const f32x4*)&gA[iv0 * 128 + c4];
        const f32x4 b0 = *(const f32x4*)&gB[iv0 * 128 + c4];
        const f32x4 a1 = *(const f32x4*)&gA[iv1 * 128 + c4];
        const f32x4 b1 = *(const f32x4*)&gB[iv1 * 128 + c4];

        const size_t off0 = (size_t)r0 * 128 + c4;
        f32x4 e0 = __builtin_nontemporal_load((const f32x4*)(ea + off0));
        f32x4 e1 = __builtin_nontemporal_load((const f32x4*)(ea + off0 + 128));
        __builtin_nontemporal_store(e0 + (len0 * a0 + b0), (f32x4*)(oute + off0));
        __builtin_nontemporal_store(e1 + (len1 * a1 + b1), (f32x4*)(oute + off0 + 128));
    }
}

// ---- node path: proven MFMA + LDS-transpose structure, node tiles only ---
// W2 LDS layout (bf16): dst = (((k>>5)*8 + (c>>4))*64 + (((k>>3)&3)*16 + (c&15)))*8 + (k&7)
__device__ __forceinline__ void stage_w2(const float* __restrict__ W2, __bf16* w2l) {
    for (int idx = threadIdx.x; idx < 128 * 128; idx += 512) {
        int k = idx >> 7;
        int c = idx & 127;
        int dst = (((k >> 5) * 8 + (c >> 4)) * 64 + (((k >> 3) & 3) * 16 + (c & 15))) * 8 + (k & 7);
        w2l[dst] = (__bf16)W2[idx];
    }
}

// Barriers are block-uniform: the node-tail wave predicate is a `valid` flag,
// never a `continue`. __syncthreads() on both sides of the transpose read is
// REQUIRED (lane-crossing through LDS has no per-thread dependence edge).
__global__ __launch_bounds__(512, 3) void node_kernel(
    const float* __restrict__ pos, const float* __restrict__ x,
    const float* __restrict__ lp, const int* __restrict__ msk,
    const float* __restrict__ Wp1, const float* __restrict__ bp1,
    const float* __restrict__ Wp2, const float* __restrict__ bp2,
    float* __restrict__ outx)
{
    __shared__ __bf16 w2l[16384];
    __shared__ float w1l[384], b1l[128], b2l[128];
    __shared__ float tbuf[8][512];   // per-wave 2 KB transpose buffer

    stage_w2(Wp2, w2l);
    for (int i = threadIdx.x; i < 384; i += 512) w1l[i] = Wp1[i];
    if (threadIdx.x < 128) {
        b1l[threadIdx.x] = bp1[threadIdx.x];
        b2l[threadIdx.x] = bp2[threadIdx.x];
    }
    __syncthreads();

    const int w = threadIdx.x >> 6;
    const int l = threadIdx.x & 63;
    const int llo = l & 15;
    const int lgrp = l >> 4;
    float* tb = tbuf[w];

    const int base = blockIdx.x * 128;
    const int e0 = base + w * 16;
    // NN % 16 == 0 -> node validity is all-or-nothing per wave.
    const bool valid = (e0 + 16 <= NN);

    f32x4 ear[8];
    f32x4 acc[8];
    if (valid) {
        const float* srow = x + (size_t)e0 * 128;
#pragma unroll
        for (int j = 0; j < 8; j++) ear[j] = *(const f32x4*)(srow + j * 256 + l * 4);

        int nd = e0 + llo;
        const float* p = msk[nd] ? lp : pos;
        float px = p[3 * nd + 0];
        float py = p[3 * nd + 1];
        float pz = p[3 * nd + 2];

#pragma unroll
        for (int m = 0; m < 8; m++) acc[m] = (f32x4){0.f, 0.f, 0.f, 0.f};

#pragma unroll
        for (int kk = 0; kk < 4; kk++) {
            bf16x8 hf;
#pragma unroll
            for (int j = 0; j < 8; j++) {
                int k = kk * 32 + lgrp * 8 + j;
                float h = px * w1l[k] + py * w1l[128 + k] + pz * w1l[256 + k] + b1l[k];
                hf[j] = (__bf16)fmaxf(h, 0.f);
            }
#pragma unroll
            for (int m = 0; m < 8; m++) {
                bf16x8 wf = *(const bf16x8*)&w2l[((kk * 8 + m) * 64 + l) * 8];
                acc[m] = __builtin_amdgcn_mfma_f32_16x16x32_bf16(wf, hf, acc[m], 0, 0, 0);
            }
        }
    }

    float* drow = outx + (size_t)e0 * 128;
    f32x4 b2v = *(const f32x4*)&b2l[(l & 31) * 4];

#pragma unroll
    for (int p = 0; p < 4; p++) {
        if (valid && (llo >> 2) == p) {
            int r = llo & 3;
#pragma unroll
            for (int m = 0; m < 8; m++) {
                int c = (m * 16 + lgrp * 4 + r * 4) & 127;   // rotate row r by r*4 floats
                *(f32x4*)&tb[r * 128 + c] = acc[m];
            }
        }
        __syncthreads();   // RAW: other lanes' writes -> this lane's reads
        if (valid) {
#pragma unroll
            for (int i = 0; i < 2; i++) {
                int row = 2 * i + (l >> 5);
                int c = ((l & 31) * 4 + row * 4) & 127;
                f32x4 tv = *(const f32x4*)&tb[row * 128 + c];
                f32x4 o = tv + b2v + ear[p * 2 + i];
                *(f32x4*)(drow + p * 512 + i * 256 + l * 4) = o;
            }
        }
        __syncthreads();   // WAR: reads done before next pass overwrites tb
    }
}

extern "C" void kernel_launch(void* const* d_in, const int* in_sizes, int n_in,
                              void* d_out, int out_size, void* d_ws, size_t ws_size,
                              hipStream_t stream) {
    const float* pos        = (const float*)d_in[0];
    const float* x          = (const float*)d_in[1];
    const float* edge_attr  = (const float*)d_in[2];
    const int* edge_index   = (const int*)d_in[3];
    const float* last_pred  = (const float*)d_in[4];
    const int* mask         = (const int*)d_in[5];
    const float* Wp1 = (const float*)d_in[6];
    const float* bp1 = (const float*)d_in[7];
    const float* Wp2 = (const float*)d_in[8];
    const float* bp2 = (const float*)d_in[9];
    const float* Wd1 = (const float*)d_in[10];
    const float* bd1 = (const float*)d_in[11];
    const float* Wd2 = (const float*)d_in[12];
    const float* bd2 = (const float*)d_in[13];

    float* outx = (float*)d_out;                    // [N,128]
    float* oute = outx + (size_t)NN * 128;          // [E,128]

    // Build the piecewise-linear tables (self-contained, one launch).
    prep_tables<<<NIV, 128, 0, stream>>>(Wd1, bd1, Wd2, bd2);

    // Node path (3% of traffic): MFMA structure, 391 tiles.
    node_kernel<<<NT_N, 512, 0, stream>>>(pos, x, last_pred, mask,
                                          Wp1, bp1, Wp2, bp2, outx);

    if (ws_size >= (size_t)EE * 8) {
        float2* lenivp = (float2*)d_ws;             // [E] {len, iv}
        leniv_kernel<<<(EE + 255) / 256, 256, 0, stream>>>(
            edge_index, pos, last_pred, mask, lenivp);
        edge_kernel<0><<<2048, 256, 0, stream>>>(
            edge_attr, lenivp, nullptr, edge_index, pos, last_pred, mask, oute);
    } else if (ws_size >= (size_t)EE * 4) {
        float* len = (float*)d_ws;                  // [E]
        len_kernel<<<(EE + 255) / 256, 256, 0, stream>>>(
            edge_index, pos, last_pred, mask, len);
        edge_kernel<1><<<2048, 256, 0, stream>>>(
            edge_attr, nullptr, len, edge_index, pos, last_pred, mask, oute);
    } else {
        edge_kernel<2><<<2048, 256, 0, stream>>>(
            edge_attr, nullptr, nullptr, edge_index, pos, last_pred, mask, oute);
    }
}

// Round 3
// 379.854 us; speedup vs baseline: 1.0160x; 1.0160x over previous
//
#include <hip/hip_runtime.h>
#include <hip/hip_bf16.h>

#define NN 50000
#define EE 1600000
#define NB_NODE 391     // ceil(NN/128) node tiles
#define NIV 129         // piecewise-linear intervals (<=128 breakpoints + 1)

typedef float f32x4 __attribute__((ext_vector_type(4)));
typedef __bf16 bf16x8 __attribute__((ext_vector_type(8)));

// Piecewise-linear tables for the edge MLP (input is a SCALAR length):
//   out[c] = len * gA[iv][c] + gB[iv][c],  iv = #{ sorted breakpoints < len }
__device__ float gT[128];                       // sorted breakpoints
__device__ __align__(16) float gA[NIV * 128];
__device__ __align__(16) float gB[NIV * 128];

__device__ __forceinline__ float edge_len(int e, const int* __restrict__ eidx,
                                          const float* __restrict__ pos,
                                          const float* __restrict__ lp,
                                          const int* __restrict__ msk) {
    int ri = eidx[e];
    int ci = eidx[EE + e];
    const float* pr = msk[ri] ? lp : pos;
    const float* pc = msk[ci] ? lp : pos;
    float dx = pr[3 * ri + 0] - pc[3 * ci + 0];
    float dy = pr[3 * ri + 1] - pc[3 * ci + 1];
    float dz = pr[3 * ri + 2] - pc[3 * ci + 2];
    return sqrtf(dx * dx + dy * dy + dz * dz);
}

// ---- combined node + prep kernel -----------------------------------------
// blocks [0, NB_NODE): proven MFMA + LDS-transpose node path (unchanged).
// blocks [NB_NODE, NB_NODE+NIV): build PWL tables, one interval per block,
// k-loop split 4-way across the 512 threads. Branch is blockIdx-uniform, so
// per-path __syncthreads() is legal. LDS overlaid via union (node needs
// ~50.5 KB; x3 blocks/CU = 155 KB <= 160 KB).
union SM {
    struct {
        __bf16 w2l[16384];
        float w1l[384], b1l[128], b2l[128];
        float tbuf[8][512];
    } n;
    struct {
        float t_s[128];
        int   rank_s[128];
        float pa[4][128], pb[4][128];
    } p;
};

// W2 LDS layout (bf16): dst = (((k>>5)*8 + (c>>4))*64 + (((k>>3)&3)*16 + (c&15)))*8 + (k&7)
__device__ __forceinline__ void stage_w2(const float* __restrict__ W2, __bf16* w2l) {
    for (int idx = threadIdx.x; idx < 128 * 128; idx += 512) {
        int k = idx >> 7;
        int c = idx & 127;
        int dst = (((k >> 5) * 8 + (c >> 4)) * 64 + (((k >> 3) & 3) * 16 + (c & 15))) * 8 + (k & 7);
        w2l[dst] = (__bf16)W2[idx];
    }
}

__global__ __launch_bounds__(512, 3) void node_prep_kernel(
    const float* __restrict__ pos, const float* __restrict__ x,
    const float* __restrict__ lp, const int* __restrict__ msk,
    const float* __restrict__ Wp1, const float* __restrict__ bp1,
    const float* __restrict__ Wp2, const float* __restrict__ bp2,
    const float* __restrict__ Wd1, const float* __restrict__ bd1,
    const float* __restrict__ Wd2, const float* __restrict__ bd2,
    float* __restrict__ outx)
{
    __shared__ SM sm;

    if (blockIdx.x >= NB_NODE) {
        // ---- prep path: interval i, channel c, k-quarter q ----
        // t_k = -b1/W1 (W1==0 -> +inf, never toggles). Strict order (t,k) ->
        // ranks are a permutation. Unit k active on interval i iff
        //   W1>0: rank<i;  W1<0: rank>=i;  W1==0: b1>0.
        const int i = blockIdx.x - NB_NODE;
        const int c = threadIdx.x & 127;
        const int q = threadIdx.x >> 7;
        if (q == 0) {
            float w1 = Wd1[c], b1 = bd1[c];
            sm.p.t_s[c] = (w1 == 0.f) ? __builtin_inff() : (-b1 / w1);
        }
        __syncthreads();
        if (q == 0) {
            float t = sm.p.t_s[c];
            int rank = 0;
            for (int j = 0; j < 128; j++) {
                float tj = sm.p.t_s[j];
                rank += (tj < t) || (tj == t && j < c);
            }
            sm.p.rank_s[c] = rank;
            if (i == 0) gT[rank] = t;   // publish sorted breakpoints once
        }
        __syncthreads();
        float a = 0.f, b = 0.f;
        for (int kk = 0; kk < 32; kk++) {
            int k = q * 32 + kk;
            float w1k = Wd1[k], b1k = bd1[k];
            bool act = (w1k > 0.f) ? (sm.p.rank_s[k] < i)
                     : (w1k < 0.f) ? (sm.p.rank_s[k] >= i)
                                   : (b1k > 0.f);
            if (act) {
                float w2 = Wd2[k * 128 + c];
                a = fmaf(w1k, w2, a);
                b = fmaf(b1k, w2, b);
            }
        }
        sm.p.pa[q][c] = a;
        sm.p.pb[q][c] = b;
        __syncthreads();
        if (q == 0) {
            float A = sm.p.pa[0][c] + sm.p.pa[1][c] + sm.p.pa[2][c] + sm.p.pa[3][c];
            float B = sm.p.pb[0][c] + sm.p.pb[1][c] + sm.p.pb[2][c] + sm.p.pb[3][c];
            gA[i * 128 + c] = A;
            gB[i * 128 + c] = B + bd2[c];
        }
        return;
    }

    // ---- node path (proven; barriers block-uniform, `valid` flag not
    // `continue`; __syncthreads REQUIRED both sides of transpose read) ----
    stage_w2(Wp2, sm.n.w2l);
    for (int i = threadIdx.x; i < 384; i += 512) sm.n.w1l[i] = Wp1[i];
    if (threadIdx.x < 128) {
        sm.n.b1l[threadIdx.x] = bp1[threadIdx.x];
        sm.n.b2l[threadIdx.x] = bp2[threadIdx.x];
    }
    __syncthreads();

    const int w = threadIdx.x >> 6;
    const int l = threadIdx.x & 63;
    const int llo = l & 15;
    const int lgrp = l >> 4;
    float* tb = sm.n.tbuf[w];

    const int e0 = blockIdx.x * 128 + w * 16;
    // NN % 16 == 0 -> node validity is all-or-nothing per wave.
    const bool valid = (e0 + 16 <= NN);

    f32x4 ear[8];
    f32x4 acc[8];
    if (valid) {
        const float* srow = x + (size_t)e0 * 128;
#pragma unroll
        for (int j = 0; j < 8; j++) ear[j] = *(const f32x4*)(srow + j * 256 + l * 4);

        int nd = e0 + llo;
        const float* p = msk[nd] ? lp : pos;
        float px = p[3 * nd + 0];
        float py = p[3 * nd + 1];
        float pz = p[3 * nd + 2];

#pragma unroll
        for (int m = 0; m < 8; m++) acc[m] = (f32x4){0.f, 0.f, 0.f, 0.f};

#pragma unroll
        for (int kk = 0; kk < 4; kk++) {
            bf16x8 hf;
#pragma unroll
            for (int j = 0; j < 8; j++) {
                int k = kk * 32 + lgrp * 8 + j;
                float h = px * sm.n.w1l[k] + py * sm.n.w1l[128 + k]
                        + pz * sm.n.w1l[256 + k] + sm.n.b1l[k];
                hf[j] = (__bf16)fmaxf(h, 0.f);
            }
#pragma unroll
            for (int m = 0; m < 8; m++) {
                bf16x8 wf = *(const bf16x8*)&sm.n.w2l[((kk * 8 + m) * 64 + l) * 8];
                acc[m] = __builtin_amdgcn_mfma_f32_16x16x32_bf16(wf, hf, acc[m], 0, 0, 0);
            }
        }
    }

    float* drow = outx + (size_t)e0 * 128;
    f32x4 b2v = *(const f32x4*)&sm.n.b2l[(l & 31) * 4];

#pragma unroll
    for (int p = 0; p < 4; p++) {
        if (valid && (llo >> 2) == p) {
            int r = llo & 3;
#pragma unroll
            for (int m = 0; m < 8; m++) {
                int c = (m * 16 + lgrp * 4 + r * 4) & 127;   // rotate row r by r*4 floats
                *(f32x4*)&tb[r * 128 + c] = acc[m];
            }
        }
        __syncthreads();   // RAW: other lanes' writes -> this lane's reads
        if (valid) {
#pragma unroll
            for (int i = 0; i < 2; i++) {
                int row = 2 * i + (l >> 5);
                int c = ((l & 31) * 4 + row * 4) & 127;
                f32x4 tv = *(const f32x4*)&tb[row * 128 + c];
                f32x4 o = tv + b2v + ear[p * 2 + i];
                *(f32x4*)(drow + p * 512 + i * 256 + l * 4) = o;
            }
        }
        __syncthreads();   // WAR: reads done before next pass overwrites tb
    }
}

// ---- edge kernel: pure stream, plain (non-NT) f32x4 loads/stores ---------
// 32 lanes per row-quad; gather+search is lane-uniform (broadcast loads from
// the L2/LLC-resident 1.4 MB pos/lp/msk set) -> no precompute pass, no
// workspace round-trip. Stream loads issued FIRST so their latency covers
// the gather/search chain.
__global__ __launch_bounds__(256) void edge_kernel(
    const float* __restrict__ ea, const int* __restrict__ eidx,
    const float* __restrict__ pos, const float* __restrict__ lp,
    const int* __restrict__ msk, float* __restrict__ oute)
{
    __shared__ float ts[128];
    if (threadIdx.x < 128) ts[threadIdx.x] = gT[threadIdx.x];
    __syncthreads();

    const int g  = threadIdx.x >> 5;          // row-quad group within block
    const int c4 = (threadIdx.x & 31) * 4;    // channel base

    for (int r0 = (blockIdx.x * 8 + g) * 4; r0 < EE; r0 += gridDim.x * 32) {
        // EE % 4 == 0 and r0 % 4 == 0 -> rows r0..r0+3 all valid.
        f32x4 e[4];
#pragma unroll
        for (int j = 0; j < 4; j++)
            e[j] = *(const f32x4*)(ea + (size_t)(r0 + j) * 128 + c4);

        float lenv[4];
        int iv[4];
#pragma unroll
        for (int j = 0; j < 4; j++) {
            lenv[j] = edge_len(r0 + j, eidx, pos, lp, msk);
            int lo = 0;            // iv = #{ ts[m] < len }, result in [0,128]
#pragma unroll
            for (int s = 128; s > 0; s >>= 1) {
                int m = lo + s;
                if (m <= 128 && ts[m - 1] < lenv[j]) lo = m;
            }
            iv[j] = lo;
        }

#pragma unroll
        for (int j = 0; j < 4; j++) {
            const f32x4 a = *(const f32x4*)&gA[iv[j] * 128 + c4];
            const f32x4 b = *(const f32x4*)&gB[iv[j] * 128 + c4];
            *(f32x4*)(oute + (size_t)(r0 + j) * 128 + c4) = e[j] + (lenv[j] * a + b);
        }
    }
}

extern "C" void kernel_launch(void* const* d_in, const int* in_sizes, int n_in,
                              void* d_out, int out_size, void* d_ws, size_t ws_size,
                              hipStream_t stream) {
    const float* pos        = (const float*)d_in[0];
    const float* x          = (const float*)d_in[1];
    const float* edge_attr  = (const float*)d_in[2];
    const int* edge_index   = (const int*)d_in[3];
    const float* last_pred  = (const float*)d_in[4];
    const int* mask         = (const int*)d_in[5];
    const float* Wp1 = (const float*)d_in[6];
    const float* bp1 = (const float*)d_in[7];
    const float* Wp2 = (const float*)d_in[8];
    const float* bp2 = (const float*)d_in[9];
    const float* Wd1 = (const float*)d_in[10];
    const float* bd1 = (const float*)d_in[11];
    const float* Wd2 = (const float*)d_in[12];
    const float* bd2 = (const float*)d_in[13];

    float* outx = (float*)d_out;                    // [N,128]
    float* oute = outx + (size_t)NN * 128;          // [E,128]

    // Launch 1: node MFMA path + PWL table build (independent block ranges).
    node_prep_kernel<<<NB_NODE + NIV, 512, 0, stream>>>(
        pos, x, last_pred, mask,
        Wp1, bp1, Wp2, bp2, Wd1, bd1, Wd2, bd2, outx);

    // Launch 2: the 1.65 GB edge stream (depends on gT/gA/gB; stream-ordered).
    edge_kernel<<<2048, 256, 0, stream>>>(
        edge_attr, edge_index, pos, last_pred, mask, oute);
}

// Round 4
// 367.693 us; speedup vs baseline: 1.0496x; 1.0331x over previous
//
#include <hip/hip_runtime.h>
#include <hip/hip_bf16.h>

#define NN 50000
#define EE 1600000
#define NB_NODE 391     // ceil(NN/128) node tiles
#define NIV 129         // piecewise-linear intervals (<=128 breakpoints + 1)

typedef float f32x4 __attribute__((ext_vector_type(4)));
typedef __bf16 bf16x8 __attribute__((ext_vector_type(8)));

// Piecewise-linear tables for the edge MLP (input is a SCALAR length):
//   out[c] = len * gA[iv][c] + gB[iv][c],  iv = #{ sorted breakpoints < len }
__device__ float gT[128];                       // sorted breakpoints
__device__ __align__(16) float gA[NIV * 128];
__device__ __align__(16) float gB[NIV * 128];

__device__ __forceinline__ float edge_len(int e, const int* __restrict__ eidx,
                                          const float* __restrict__ pos,
                                          const float* __restrict__ lp,
                                          const int* __restrict__ msk) {
    int ri = eidx[e];
    int ci = eidx[EE + e];
    const float* pr = msk[ri] ? lp : pos;
    const float* pc = msk[ci] ? lp : pos;
    float dx = pr[3 * ri + 0] - pc[3 * ci + 0];
    float dy = pr[3 * ri + 1] - pc[3 * ci + 1];
    float dz = pr[3 * ri + 2] - pc[3 * ci + 2];
    return sqrtf(dx * dx + dy * dy + dz * dz);
}

// ---- combined node + prep kernel (unchanged, proven R3) ------------------
union SM {
    struct {
        __bf16 w2l[16384];
        float w1l[384], b1l[128], b2l[128];
        float tbuf[8][512];
    } n;
    struct {
        float t_s[128];
        int   rank_s[128];
        float pa[4][128], pb[4][128];
    } p;
};

// W2 LDS layout (bf16): dst = (((k>>5)*8 + (c>>4))*64 + (((k>>3)&3)*16 + (c&15)))*8 + (k&7)
__device__ __forceinline__ void stage_w2(const float* __restrict__ W2, __bf16* w2l) {
    for (int idx = threadIdx.x; idx < 128 * 128; idx += 512) {
        int k = idx >> 7;
        int c = idx & 127;
        int dst = (((k >> 5) * 8 + (c >> 4)) * 64 + (((k >> 3) & 3) * 16 + (c & 15))) * 8 + (k & 7);
        w2l[dst] = (__bf16)W2[idx];
    }
}

__global__ __launch_bounds__(512, 3) void node_prep_kernel(
    const float* __restrict__ pos, const float* __restrict__ x,
    const float* __restrict__ lp, const int* __restrict__ msk,
    const float* __restrict__ Wp1, const float* __restrict__ bp1,
    const float* __restrict__ Wp2, const float* __restrict__ bp2,
    const float* __restrict__ Wd1, const float* __restrict__ bd1,
    const float* __restrict__ Wd2, const float* __restrict__ bd2,
    float* __restrict__ outx)
{
    __shared__ SM sm;

    if (blockIdx.x >= NB_NODE) {
        // ---- prep path: interval i, channel c, k-quarter q ----
        // t_k = -b1/W1 (W1==0 -> +inf, never toggles). Strict order (t,k) ->
        // ranks are a permutation. Unit k active on interval i iff
        //   W1>0: rank<i;  W1<0: rank>=i;  W1==0: b1>0.
        const int i = blockIdx.x - NB_NODE;
        const int c = threadIdx.x & 127;
        const int q = threadIdx.x >> 7;
        if (q == 0) {
            float w1 = Wd1[c], b1 = bd1[c];
            sm.p.t_s[c] = (w1 == 0.f) ? __builtin_inff() : (-b1 / w1);
        }
        __syncthreads();
        if (q == 0) {
            float t = sm.p.t_s[c];
            int rank = 0;
            for (int j = 0; j < 128; j++) {
                float tj = sm.p.t_s[j];
                rank += (tj < t) || (tj == t && j < c);
            }
            sm.p.rank_s[c] = rank;
            if (i == 0) gT[rank] = t;   // publish sorted breakpoints once
        }
        __syncthreads();
        float a = 0.f, b = 0.f;
        for (int kk = 0; kk < 32; kk++) {
            int k = q * 32 + kk;
            float w1k = Wd1[k], b1k = bd1[k];
            bool act = (w1k > 0.f) ? (sm.p.rank_s[k] < i)
                     : (w1k < 0.f) ? (sm.p.rank_s[k] >= i)
                                   : (b1k > 0.f);
            if (act) {
                float w2 = Wd2[k * 128 + c];
                a = fmaf(w1k, w2, a);
                b = fmaf(b1k, w2, b);
            }
        }
        sm.p.pa[q][c] = a;
        sm.p.pb[q][c] = b;
        __syncthreads();
        if (q == 0) {
            float A = sm.p.pa[0][c] + sm.p.pa[1][c] + sm.p.pa[2][c] + sm.p.pa[3][c];
            float B = sm.p.pb[0][c] + sm.p.pb[1][c] + sm.p.pb[2][c] + sm.p.pb[3][c];
            gA[i * 128 + c] = A;
            gB[i * 128 + c] = B + bd2[c];
        }
        return;
    }

    // ---- node path (proven; barriers block-uniform, `valid` flag not
    // `continue`; __syncthreads REQUIRED both sides of transpose read) ----
    stage_w2(Wp2, sm.n.w2l);
    for (int i = threadIdx.x; i < 384; i += 512) sm.n.w1l[i] = Wp1[i];
    if (threadIdx.x < 128) {
        sm.n.b1l[threadIdx.x] = bp1[threadIdx.x];
        sm.n.b2l[threadIdx.x] = bp2[threadIdx.x];
    }
    __syncthreads();

    const int w = threadIdx.x >> 6;
    const int l = threadIdx.x & 63;
    const int llo = l & 15;
    const int lgrp = l >> 4;
    float* tb = sm.n.tbuf[w];

    const int e0 = blockIdx.x * 128 + w * 16;
    // NN % 16 == 0 -> node validity is all-or-nothing per wave.
    const bool valid = (e0 + 16 <= NN);

    f32x4 ear[8];
    f32x4 acc[8];
    if (valid) {
        const float* srow = x + (size_t)e0 * 128;
#pragma unroll
        for (int j = 0; j < 8; j++) ear[j] = *(const f32x4*)(srow + j * 256 + l * 4);

        int nd = e0 + llo;
        const float* p = msk[nd] ? lp : pos;
        float px = p[3 * nd + 0];
        float py = p[3 * nd + 1];
        float pz = p[3 * nd + 2];

#pragma unroll
        for (int m = 0; m < 8; m++) acc[m] = (f32x4){0.f, 0.f, 0.f, 0.f};

#pragma unroll
        for (int kk = 0; kk < 4; kk++) {
            bf16x8 hf;
#pragma unroll
            for (int j = 0; j < 8; j++) {
                int k = kk * 32 + lgrp * 8 + j;
                float h = px * sm.n.w1l[k] + py * sm.n.w1l[128 + k]
                        + pz * sm.n.w1l[256 + k] + sm.n.b1l[k];
                hf[j] = (__bf16)fmaxf(h, 0.f);
            }
#pragma unroll
            for (int m = 0; m < 8; m++) {
                bf16x8 wf = *(const bf16x8*)&sm.n.w2l[((kk * 8 + m) * 64 + l) * 8];
                acc[m] = __builtin_amdgcn_mfma_f32_16x16x32_bf16(wf, hf, acc[m], 0, 0, 0);
            }
        }
    }

    float* drow = outx + (size_t)e0 * 128;
    f32x4 b2v = *(const f32x4*)&sm.n.b2l[(l & 31) * 4];

#pragma unroll
    for (int p = 0; p < 4; p++) {
        if (valid && (llo >> 2) == p) {
            int r = llo & 3;
#pragma unroll
            for (int m = 0; m < 8; m++) {
                int c = (m * 16 + lgrp * 4 + r * 4) & 127;   // rotate row r by r*4 floats
                *(f32x4*)&tb[r * 128 + c] = acc[m];
            }
        }
        __syncthreads();   // RAW: other lanes' writes -> this lane's reads
        if (valid) {
#pragma unroll
            for (int i = 0; i < 2; i++) {
                int row = 2 * i + (l >> 5);
                int c = ((l & 31) * 4 + row * 4) & 127;
                f32x4 tv = *(const f32x4*)&tb[row * 128 + c];
                f32x4 o = tv + b2v + ear[p * 2 + i];
                *(f32x4*)(drow + p * 512 + i * 256 + l * 4) = o;
            }
        }
        __syncthreads();   // WAR: reads done before next pass overwrites tb
    }
}

// ---- gather kernel: length AND interval index, once per edge -------------
__global__ __launch_bounds__(256) void leniv_kernel(
    const int* __restrict__ eidx, const float* __restrict__ pos,
    const float* __restrict__ lp, const int* __restrict__ msk,
    float2* __restrict__ lenivp)
{
    __shared__ float ts[128];
    if (threadIdx.x < 128) ts[threadIdx.x] = gT[threadIdx.x];
    __syncthreads();
    int e = blockIdx.x * 256 + threadIdx.x;
    if (e < EE) {
        float lv = edge_len(e, eidx, pos, lp, msk);
        int lo = 0;            // iv = #{ ts[j] < lv }, result in [0,128]
#pragma unroll
        for (int s = 128; s > 0; s >>= 1) {
            int m = lo + s;
            if (m <= 128 && ts[m - 1] < lv) lo = m;
        }
        lenivp[e] = make_float2(lv, (float)lo);   // iv<=128 exact in f32
    }
}

// ---- edge kernel: pure stream with PERFECT 1KB/instruction coalescing ----
// Lane's row = r0 + (l>>5), channel = (l&31)*4: every wave64 stream
// load/store covers 2 consecutive rows = 64 lanes x 16 B = 1 KB CONTIGUOUS
// (previous rounds' (tid&31) mapping split every VMEM op into two 512 B
// segments 2 KB apart — the one structural constant across R1-R3).
// Per row-pair: one 8 B half-wave-uniform {len,iv} load + two L1-hot table
// loads. Block = 4 waves x 8 rows = 32 rows/iter.
template <bool PRE>
__global__ __launch_bounds__(256) void edge_kernel(
    const float* __restrict__ ea, const float2* __restrict__ lenivp,
    const int* __restrict__ eidx, const float* __restrict__ pos,
    const float* __restrict__ lp, const int* __restrict__ msk,
    float* __restrict__ oute)
{
    __shared__ float ts[128];
    if (!PRE) {
        if (threadIdx.x < 128) ts[threadIdx.x] = gT[threadIdx.x];
        __syncthreads();
    }

    const int w  = threadIdx.x >> 6;          // wave id (0..3)
    const int l  = threadIdx.x & 63;
    const int c4 = (l & 31) * 4;              // channel base within the row
    const int rh = l >> 5;                    // which row of the pair

    for (int base = blockIdx.x * 32 + w * 8; base < EE; base += gridDim.x * 32) {
        // EE % 32 == 0 -> all 8 rows of this wave valid.
        f32x4 e[4];
#pragma unroll
        for (int j = 0; j < 4; j++)           // 1 KB contiguous per load
            e[j] = *(const f32x4*)(ea + (size_t)(base + 2 * j) * 128 + l * 4);

        float lenv[4];
        int iv[4];
#pragma unroll
        for (int j = 0; j < 4; j++) {
            int r = base + 2 * j + rh;        // this lane's row
            if (PRE) {
                float2 f2 = lenivp[r];        // 8 B, uniform per half-wave
                lenv[j] = f2.x;
                iv[j] = (int)f2.y;
            } else {
                lenv[j] = edge_len(r, eidx, pos, lp, msk);
                int lo = 0;
#pragma unroll
                for (int s = 128; s > 0; s >>= 1) {
                    int m = lo + s;
                    if (m <= 128 && ts[m - 1] < lenv[j]) lo = m;
                }
                iv[j] = lo;
            }
        }

#pragma unroll
        for (int j = 0; j < 4; j++) {
            const f32x4 a = *(const f32x4*)&gA[iv[j] * 128 + c4];
            const f32x4 b = *(const f32x4*)&gB[iv[j] * 128 + c4];
            *(f32x4*)(oute + (size_t)(base + 2 * j) * 128 + l * 4) =
                e[j] + (lenv[j] * a + b);     // 1 KB contiguous per store
        }
    }
}

extern "C" void kernel_launch(void* const* d_in, const int* in_sizes, int n_in,
                              void* d_out, int out_size, void* d_ws, size_t ws_size,
                              hipStream_t stream) {
    const float* pos        = (const float*)d_in[0];
    const float* x          = (const float*)d_in[1];
    const float* edge_attr  = (const float*)d_in[2];
    const int* edge_index   = (const int*)d_in[3];
    const float* last_pred  = (const float*)d_in[4];
    const int* mask         = (const int*)d_in[5];
    const float* Wp1 = (const float*)d_in[6];
    const float* bp1 = (const float*)d_in[7];
    const float* Wp2 = (const float*)d_in[8];
    const float* bp2 = (const float*)d_in[9];
    const float* Wd1 = (const float*)d_in[10];
    const float* bd1 = (const float*)d_in[11];
    const float* Wd2 = (const float*)d_in[12];
    const float* bd2 = (const float*)d_in[13];

    float* outx = (float*)d_out;                    // [N,128]
    float* oute = outx + (size_t)NN * 128;          // [E,128]

    // Launch 1: node MFMA path + PWL table build (independent block ranges).
    node_prep_kernel<<<NB_NODE + NIV, 512, 0, stream>>>(
        pos, x, last_pred, mask,
        Wp1, bp1, Wp2, bp2, Wd1, bd1, Wd2, bd2, outx);

    if (ws_size >= (size_t)EE * 8) {
        float2* lenivp = (float2*)d_ws;             // [E] {len, iv}
        leniv_kernel<<<(EE + 255) / 256, 256, 0, stream>>>(
            edge_index, pos, last_pred, mask, lenivp);
        edge_kernel<true><<<2048, 256, 0, stream>>>(
            edge_attr, lenivp, edge_index, pos, last_pred, mask, oute);
    } else {
        edge_kernel<false><<<2048, 256, 0, stream>>>(
            edge_attr, nullptr, edge_index, pos, last_pred, mask, oute);
    }
}